// Round 12
// baseline (1379.732 us; speedup 1.0000x reference)
//
#include <hip/hip_runtime.h>
#include <cmath>

typedef __attribute__((ext_vector_type(8))) short short8;
typedef __attribute__((ext_vector_type(4))) float f32x4;
typedef __attribute__((ext_vector_type(16))) float f32x16;
typedef unsigned short u16;

#define NB   16
#define NC   128
#define NS   64
#define NW   64
#define NHH  128
#define GSTR (NHH * NC * 3)

// workspace layout (bytes)
#define WI_OFF 0u            // Wi packed: 512*256*2 = 262144
#define WS_OFF 262144u       // Ws packed (32x32 A-frag): 512*384*2 = 393216
#define FS_OFF 1048576u      // fs (bias included): 1024 * 512*64 * 2 = 67108864
#define WS_NEEDED (FS_OFF + (size_t)NB * NS * 512 * NW * 2)

__device__ __forceinline__ u16 f2bf(float f) {
    unsigned u = __builtin_bit_cast(unsigned, f);
    u += 0x7fffu + ((u >> 16) & 1u);
    return (u16)(u >> 16);
}
__device__ __forceinline__ float bfreg(uint2 u, int r) {
    unsigned w = (r < 2) ? u.x : u.y;
    unsigned bits = (r & 1) ? (w & 0xffff0000u) : (w << 16);
    return __builtin_bit_cast(float, bits);
}
__device__ __forceinline__ float fsig(float x) {
    return __builtin_amdgcn_rcpf(1.f + __builtin_amdgcn_exp2f(x * -1.442695041f));
}
__device__ __forceinline__ float ftanh(float x) {
    return 1.f - 2.f * __builtin_amdgcn_rcpf(1.f + __builtin_amdgcn_exp2f(x * 2.885390082f));
}
// 32x32x16 MFMA, accumulator forced into AGPRs (R10-validated technique).
__device__ __forceinline__ void mfma32(f32x16& acc, short8 a, short8 b) {
    asm volatile("v_mfma_f32_32x32x16_bf16 %0, %1, %2, %0"
                 : "+a"(acc) : "v"(a), "v"(b));
}
// Dependency-carrying hazard pads (R10-validated): accvgpr_write -> mfma srcC,
// and mfma -> accvgpr_read. Operands force ordering; s_nops cover wait-states.
#define PAD8(A)  asm volatile("s_nop 7" \
    : "+a"(A[0][0]), "+a"(A[0][1]), "+a"(A[1][0]), "+a"(A[1][1]), \
      "+a"(A[2][0]), "+a"(A[2][1]), "+a"(A[3][0]), "+a"(A[3][1]))
#define PAD24(A) asm volatile("s_nop 7\ns_nop 7\ns_nop 7" \
    : "+a"(A[0][0]), "+a"(A[0][1]), "+a"(A[1][0]), "+a"(A[1][1]), \
      "+a"(A[2][0]), "+a"(A[2][1]), "+a"(A[3][0]), "+a"(A[3][1]))

// ---------------- phase 0: pack weights -------------------------------------
// Wi (16x16 A-frag, for itos): wip[(((W*4+g)*8+kt)*64+l)*8+j],
//   m=128g+16W+(l&15), k=kt*32+(l>>4)*8+j -> (dy=k>>7, c=k&127); row 2 masked.
// Ws (32x32 A-frag, for rec): wsp2[(((p*4+g)*24+kc)*512 + l*8 + j],
//   m=128g+32p+(l&31), k=16kc+8*(l>>5)+j -> (d=kc>>3, ch=16*(kc&7)+8*(l>>5)+j)
__global__ void pack_weights(const float* __restrict__ w_itos,
                             const float* __restrict__ w_stos,
                             u16* __restrict__ wip, u16* __restrict__ wsp2) {
    int e = blockIdx.x * 256 + threadIdx.x;
    if (e < 131072) {
        int j = e & 7, l = (e >> 3) & 63, kt = (e >> 9) & 7, wvg = e >> 12;
        int wv = wvg >> 2, g = wvg & 3;
        int m = 128 * g + 16 * wv + (l & 15);
        int k = kt * 32 + (l >> 4) * 8 + j;
        int dy = k >> 7, c = k & 127;
        wip[e] = f2bf(w_itos[(m * 128 + c) * 3 + dy]);
    } else if (e < 327680) {
        int e2 = e - 131072;              // [0, 196608)
        int j = e2 & 7;
        int l = (e2 >> 3) & 63;
        int kq = e2 >> 9;                  // [0, 384)
        int kc = kq % 24, pg = kq / 24;    // pg in [0,16)
        int p = pg >> 2, g = pg & 3;
        int m = 128 * g + 32 * p + (l & 31);
        int ch = 16 * (kc & 7) + 8 * (l >> 5) + j;
        int d = kc >> 3;
        wsp2[e2] = f2bf(w_stos[(m * 128 + ch) * 3 + d]);
    }
}

// ---------------- phase 1: input-to-state conv (validated, unchanged) --------
__global__ __launch_bounds__(512, 2) void itos_gemm(
    const float* __restrict__ image, const u16* __restrict__ wip,
    const float* __restrict__ b_itos, const float* __restrict__ b_stos,
    uint2* __restrict__ fsp) {
    const int bs = blockIdx.x, b = bs >> 6, s = bs & 63;
    const int t = threadIdx.x, wv = t >> 6, l = t & 63, lr = l & 15, lk = l >> 4;
    __shared__ u16 ImgT[64 * 256];

    {
        const int r = t >> 1, half = t & 1;
        const int dy = r >> 7, c = r & 127;
        const int s0 = s - 1 + dy;
        float v[32];
        if (s0 >= 0) {
            const float* src = image + (((size_t)b * NC + c) * NS + s0) * NW + half * 32;
            #pragma unroll
            for (int qq = 0; qq < 8; ++qq) {
                float4 f = *(const float4*)(src + 4 * qq);
                v[4*qq] = f.x; v[4*qq+1] = f.y; v[4*qq+2] = f.z; v[4*qq+3] = f.w;
            }
        } else {
            #pragma unroll
            for (int qq = 0; qq < 32; ++qq) v[qq] = 0.f;
        }
        #pragma unroll
        for (int qq = 0; qq < 32; ++qq) {
            int w = half * 32 + qq;
            ImgT[w * 256 + (r ^ ((w & 7) << 3))] = f2bf(v[qq]);
        }
    }
    __syncthreads();

    f32x4 acc[4][4];
    #pragma unroll
    for (int g = 0; g < 4; ++g)
        #pragma unroll
        for (int n = 0; n < 4; ++n) acc[g][n] = (f32x4){0.f, 0.f, 0.f, 0.f};

    #pragma unroll
    for (int kt = 0; kt < 8; ++kt) {
        short8 a[4], bb[4];
        #pragma unroll
        for (int g = 0; g < 4; ++g)
            a[g] = *(const short8*)(wip + (((wv * 4 + g) * 8 + kt) * 64 + l) * 8);
        const int cu = kt * 32 + lk * 8;
        #pragma unroll
        for (int n = 0; n < 4; ++n) {
            const int w = n * 16 + lr;
            bb[n] = *(const short8*)&ImgT[w * 256 + (cu ^ ((w & 7) << 3))];
        }
        #pragma unroll
        for (int g = 0; g < 4; ++g)
            #pragma unroll
            for (int n = 0; n < 4; ++n)
                acc[g][n] = __builtin_amdgcn_mfma_f32_16x16x32_bf16(a[g], bb[n], acc[g][n], 0, 0, 0);
    }

    float bias[4][4];
    #pragma unroll
    for (int g = 0; g < 4; ++g)
        #pragma unroll
        for (int r = 0; r < 4; ++r) {
            int m = 128 * g + 16 * wv + lk * 4 + r;
            bias[g][r] = b_itos[m] + b_stos[m];
        }

    uint2* dst = fsp + ((size_t)bs * 8 + wv) * 1024 + l;
    #pragma unroll
    for (int g = 0; g < 4; ++g)
        #pragma unroll
        for (int n = 0; n < 4; ++n) {
            uint2 u;
            u.x = (unsigned)f2bf(acc[g][n][0] + bias[g][0]) | ((unsigned)f2bf(acc[g][n][1] + bias[g][1]) << 16);
            u.y = (unsigned)f2bf(acc[g][n][2] + bias[g][2]) | ((unsigned)f2bf(acc[g][n][3] + bias[g][3]) << 16);
            dst[(g * 4 + n) * 64] = u;
        }
}

// ---------------- phase 2: recurrent, 32x32 MFMA, 4 waves, in-wave gating ----
// Wave p owns nh in [32p,32p+32), ALL 4 gates, ALL 64 w (2 n-tiles of 32).
// acc[4][2] f32x16 = 128 AGPRs. Weights: 96 KB/wave/step from L2, no dup.
// bb shared across the 4 gates -> only 48 ds_read_b128 per wave per step.
// Gating fully in-wave (lane holds i,g,f,o for its 32 (nh,w) elems).
// fs gathered from the validated 16x16-fragment fsp layout:
//   acc[g][nt][4q+r] <- uint2 at ((bs*8 + 2p+(q>>1))*1024
//                                 + (g*4+2nt)*64 + lA + 32*(q&1)), comp r,
//   lA = (l&15) + ((l>>4)&1)*64 + (l>>5)*16.
__global__ __launch_bounds__(256, 1) void rowlstm_32(
    const u16* __restrict__ wsp2, const uint2* __restrict__ fsp,
    const float* __restrict__ h0, const float* __restrict__ c0,
    float* __restrict__ out) {
    const int b = blockIdx.x;
    const int t = threadIdx.x, l = t & 63, p = t >> 6;
    const int hi = l >> 5, l31 = l & 31;
    __shared__ u16 Ht[2 * 8448];   // two buffers: [66][128] u16, rows 0/65 halo

    // zero halo rows (wh = 0, 65) in both buffers
    for (int i = t; i < 512; i += 256) {
        const int buf = (i >> 8) ? 8448 : 0;
        const int row = ((i >> 7) & 1) ? 65 : 0;
        Ht[buf + row * 128 + (i & 127)] = 0;
    }
    // h0 into buffer 0
    #pragma unroll
    for (int j = 0; j < 32; ++j) {
        int e = t * 32 + j, nh = e >> 6, w = e & 63, wh = w + 1;
        Ht[wh * 128 + (nh ^ ((wh & 7) << 3))] = f2bf(h0[e]);
    }

    // cell state: c_r[nt*16 + 4q + r] for nh = 32p+8q+4hi+r, w = 32nt+l31
    float c_r[32];
    #pragma unroll
    for (int nt = 0; nt < 2; ++nt)
        #pragma unroll
        for (int q = 0; q < 4; ++q)
            #pragma unroll
            for (int r = 0; r < 4; ++r)
                c_r[nt * 16 + 4 * q + r] =
                    c0[(32 * p + 8 * q + 4 * hi + r) * 64 + 32 * nt + l31];

    const int lA = (l & 15) + ((l >> 4) & 1) * 64 + hi * 16;
    const u16* wbase = wsp2 + (size_t)p * 4 * 24 * 512 + l * 8;

    __syncthreads();

    // prologue: fs for s = 0
    uint2 fsU[4][2][4];
    #pragma unroll
    for (int g = 0; g < 4; ++g)
        #pragma unroll
        for (int nt = 0; nt < 2; ++nt)
            #pragma unroll
            for (int q = 0; q < 4; ++q)
                fsU[g][nt][q] = fsp[((size_t)(b * 64 + 0) * 8 + 2 * p + (q >> 1)) * 1024
                                    + (g * 4 + 2 * nt) * 64 + lA + 32 * (q & 1)];

    unsigned cur = 0;
    for (int s = 0; s < NS; ++s) {
        // acc init from fs (bias folded in at itos time)
        f32x16 acc[4][2];
        #pragma unroll
        for (int g = 0; g < 4; ++g)
            #pragma unroll
            for (int nt = 0; nt < 2; ++nt)
                #pragma unroll
                for (int reg = 0; reg < 16; ++reg)
                    acc[g][nt][reg] = bfreg(fsU[g][nt][reg >> 2], reg & 3);
        PAD8(acc);   // accvgpr_write -> mfma srcC

        #pragma unroll
        for (int kc = 0; kc < 24; ++kc) {
            const int d = kc >> 3;
            const int C8 = 2 * (kc & 7) + hi;
            short8 bb0, bb1;
            {
                const int wh0 = l31 + d;
                bb0 = *(const short8*)&Ht[cur + wh0 * 128 + ((C8 ^ (wh0 & 7)) << 3)];
                const int wh1 = 32 + l31 + d;
                bb1 = *(const short8*)&Ht[cur + wh1 * 128 + ((C8 ^ (wh1 & 7)) << 3)];
            }
            #pragma unroll
            for (int g = 0; g < 4; ++g) {
                short8 a = *(const short8*)(wbase + ((size_t)(g * 24 + kc)) * 512);
                mfma32(acc[g][0], a, bb0);
                mfma32(acc[g][1], a, bb1);
            }
        }
        PAD24(acc);  // mfma -> accvgpr_read

        // prefetch next step's fs (overlaps epilogue; survives lgkm-only barrier)
        if (s < NS - 1) {
            #pragma unroll
            for (int g = 0; g < 4; ++g)
                #pragma unroll
                for (int nt = 0; nt < 2; ++nt)
                    #pragma unroll
                    for (int q = 0; q < 4; ++q)
                        fsU[g][nt][q] = fsp[((size_t)(b * 64 + s + 1) * 8 + 2 * p + (q >> 1)) * 1024
                                            + (g * 4 + 2 * nt) * 64 + lA + 32 * (q & 1)];
        }

        // in-wave gating epilogue; h_new = c_OLD * sigmoid(o)
        const unsigned nxt = cur ^ 8448;
        #pragma unroll
        for (int nt = 0; nt < 2; ++nt) {
            const int w = 32 * nt + l31;
            #pragma unroll
            for (int q = 0; q < 4; ++q) {
                u16 hb[4];
                #pragma unroll
                for (int r = 0; r < 4; ++r) {
                    const int reg = 4 * q + r;
                    const float si = fsig(acc[0][nt][reg]);
                    const float tg = ftanh(acc[1][nt][reg]);
                    const float sf = fsig(acc[2][nt][reg]);
                    const float so = fsig(acc[3][nt][reg]);
                    const int ci = nt * 16 + reg;
                    const float cold = c_r[ci];
                    c_r[ci] = sf * cold + si * tg;
                    const float hn = cold * so;
                    out[((size_t)(b * NHH + 32 * p + 8 * q + 4 * hi + r)) * (NS * NW)
                        + s * NW + w] = hn;
                    hb[r] = f2bf(hn);
                }
                uint2 hw;
                hw.x = (unsigned)hb[0] | ((unsigned)hb[1] << 16);
                hw.y = (unsigned)hb[2] | ((unsigned)hb[3] << 16);
                const int nh0 = 32 * p + 8 * q + 4 * hi;
                const int wh = w + 1;
                *(uint2*)&Ht[nxt + wh * 128 + (nh0 ^ ((wh & 7) << 3))] = hw;
            }
        }

        // single barrier per step: drain LDS only; vmem stays in flight
        asm volatile("s_waitcnt lgkmcnt(0)" ::: "memory");
        __builtin_amdgcn_s_barrier();
        asm volatile("" ::: "memory");
        cur = nxt;
    }
}

// ---------------- fallback (validated round-1 fp32 kernel) --------------------
__global__ __launch_bounds__(512, 2) void rowlstm_f32(
    const float* __restrict__ image, const float* __restrict__ w_itos,
    const float* __restrict__ b_itos, const float* __restrict__ w_stos,
    const float* __restrict__ b_stos, const float* __restrict__ h0,
    const float* __restrict__ c0, float* __restrict__ out) {
    const int b = blockIdx.x, t = threadIdx.x, wq = t & 3, nh = t >> 2, w0 = wq * 16;
    __shared__ float h_lds[NHH][NW + 2];
    #pragma unroll
    for (int j = 0; j < 16; ++j) h_lds[nh][1 + w0 + j] = h0[nh * NW + w0 + j];
    if (wq == 0) { h_lds[nh][0] = 0.f; h_lds[nh][NW + 1] = 0.f; }
    float c_r[16];
    #pragma unroll
    for (int j = 0; j < 16; ++j) c_r[j] = c0[nh * NW + w0 + j];
    const float bias[4] = {
        b_itos[0 * NHH + nh] + b_stos[0 * NHH + nh], b_itos[1 * NHH + nh] + b_stos[1 * NHH + nh],
        b_itos[2 * NHH + nh] + b_stos[2 * NHH + nh], b_itos[3 * NHH + nh] + b_stos[3 * NHH + nh]};
    const float* img_b = image + (size_t)b * NC * NS * NW;
    __syncthreads();
    for (int s = 0; s < NS; ++s) {
        float acc[4][16];
        #pragma unroll
        for (int g = 0; g < 4; ++g)
            #pragma unroll
            for (int j = 0; j < 16; ++j) acc[g][j] = bias[g];
        #pragma unroll 2
        for (int ci = 0; ci < NC; ++ci) {
            float imp[16], imc[16];
            const float* iprow = img_b + ((size_t)ci * NS + s) * NW + w0;
            #pragma unroll
            for (int qq = 0; qq < 4; ++qq) {
                float4 vv = *(const float4*)(iprow + 4 * qq);
                imc[4*qq] = vv.x; imc[4*qq+1] = vv.y; imc[4*qq+2] = vv.z; imc[4*qq+3] = vv.w;
            }
            if (s > 0) {
                #pragma unroll
                for (int qq = 0; qq < 4; ++qq) {
                    float4 vv = *(const float4*)(iprow - NW + 4 * qq);
                    imp[4*qq] = vv.x; imp[4*qq+1] = vv.y; imp[4*qq+2] = vv.z; imp[4*qq+3] = vv.w;
                }
            } else {
                #pragma unroll
                for (int j = 0; j < 16; ++j) imp[j] = 0.f;
            }
            float hv[18];
            #pragma unroll
            for (int j = 0; j < 18; ++j) hv[j] = h_lds[ci][w0 + j];
            const float* wip2 = w_itos + ((size_t)nh * NC + ci) * 3;
            const float* wsp2f = w_stos + ((size_t)nh * NHH + ci) * 3;
            #pragma unroll
            for (int g = 0; g < 4; ++g) {
                const float wi0 = wip2[(size_t)g * GSTR + 0], wi1 = wip2[(size_t)g * GSTR + 1];
                const float ws0 = wsp2f[(size_t)g * GSTR + 0], ws1 = wsp2f[(size_t)g * GSTR + 1],
                            ws2 = wsp2f[(size_t)g * GSTR + 2];
                #pragma unroll
                for (int j = 0; j < 16; ++j)
                    acc[g][j] += wi0 * imp[j] + wi1 * imc[j] + ws0 * hv[j] + ws1 * hv[j+1] + ws2 * hv[j+2];
            }
        }
        float hn[16];
        #pragma unroll
        for (int j = 0; j < 16; ++j) {
            const float si = 1.f / (1.f + __expf(-acc[0][j]));
            const float tg = tanhf(acc[1][j]);
            const float sf = 1.f / (1.f + __expf(-acc[2][j]));
            const float so = 1.f / (1.f + __expf(-acc[3][j]));
            const float cold = c_r[j];
            c_r[j] = sf * cold + si * tg;
            hn[j] = cold * so;
        }
        __syncthreads();
        #pragma unroll
        for (int j = 0; j < 16; ++j) h_lds[nh][1 + w0 + j] = hn[j];
        float* opp = out + (((size_t)b * NHH + nh) * NS + s) * NW + w0;
        #pragma unroll
        for (int qq = 0; qq < 4; ++qq)
            *(float4*)(opp + 4 * qq) = make_float4(hn[4*qq], hn[4*qq+1], hn[4*qq+2], hn[4*qq+3]);
        __syncthreads();
    }
}

extern "C" void kernel_launch(void* const* d_in, const int* in_sizes, int n_in,
                              void* d_out, int out_size, void* d_ws, size_t ws_size,
                              hipStream_t stream) {
    const float* image  = (const float*)d_in[0];
    const float* w_itos = (const float*)d_in[1];
    const float* b_itos = (const float*)d_in[2];
    const float* w_stos = (const float*)d_in[3];
    const float* b_stos = (const float*)d_in[4];
    const float* h0     = (const float*)d_in[5];
    const float* c0     = (const float*)d_in[6];
    float* out = (float*)d_out;

    if (ws_size >= WS_NEEDED) {
        u16*   wip  = (u16*)((char*)d_ws + WI_OFF);
        u16*   wsp2 = (u16*)((char*)d_ws + WS_OFF);
        uint2* fsp  = (uint2*)((char*)d_ws + FS_OFF);
        pack_weights<<<1280, 256, 0, stream>>>(w_itos, w_stos, wip, wsp2);
        itos_gemm<<<1024, 512, 0, stream>>>(image, wip, b_itos, b_stos, fsp);
        rowlstm_32<<<NB, 256, 0, stream>>>(wsp2, fsp, h0, c0, out);
    } else {
        rowlstm_f32<<<NB, 512, 0, stream>>>(image, w_itos, b_itos, w_stos, b_stos, h0, c0, out);
    }
}